// Round 1
// baseline (477.471 us; speedup 1.0000x reference)
//
#include <hip/hip_runtime.h>
#include <hip/hip_bf16.h>

// Problem constants (fixed)
#define B_ 4
#define T_ 2048
#define D_ 1024
#define H_ 16
// DK = DV = 64

typedef __attribute__((ext_vector_type(8))) short bf16x8;
typedef __attribute__((ext_vector_type(4))) float f32x4;
typedef __attribute__((ext_vector_type(4))) unsigned short u16x4;

__device__ __forceinline__ unsigned short f2bf(float x) {
  union { float f; unsigned u; } v; v.f = x;
  unsigned r = v.u + 0x7fffu + ((v.u >> 16) & 1u);   // RNE
  return (unsigned short)(r >> 16);
}

__device__ __forceinline__ void gload_lds16(const void* g, void* l) {
  __builtin_amdgcn_global_load_lds(
      (const __attribute__((address_space(1))) unsigned int*)g,
      (__attribute__((address_space(3))) unsigned int*)l, 16, 0, 0);
}

#define MFMA16(a, b, c) __builtin_amdgcn_mfma_f32_16x16x32_bf16((a), (b), (c), 0, 0, 0)

// ---------------------------------------------------------------------------
// f32 -> bf16 flat convert (vectorized 4/lane)
// ---------------------------------------------------------------------------
__global__ __launch_bounds__(256) void conv_f32_bf16(
    const float4* __restrict__ src, u16x4* __restrict__ dst, int n4) {
  int i = blockIdx.x * 256 + threadIdx.x;
  int stride = gridDim.x * 256;
  for (; i < n4; i += stride) {
    float4 v = src[i];
    u16x4 o;
    o[0] = f2bf(v.x); o[1] = f2bf(v.y); o[2] = f2bf(v.z); o[3] = f2bf(v.w);
    dst[i] = o;
  }
}

// ---------------------------------------------------------------------------
// Weight transpose: src [H][D][DK] f32  ->  dst [H*DK][D] bf16  (B^T layout)
// 64x64 tiles via LDS, +1 pad
// ---------------------------------------------------------------------------
__global__ __launch_bounds__(256) void transpose_w(
    const float* __restrict__ src, unsigned short* __restrict__ dst,
    int D, int DK, int tilesD, int tilesK) {
  __shared__ float tile[64][65];
  int bid = blockIdx.x;
  int h = bid / (tilesD * tilesK);
  int rem = bid % (tilesD * tilesK);
  int dt = rem / tilesK, ktile = rem % tilesK;
  int d0 = dt * 64, k0 = ktile * 64;
  int tx = threadIdx.x & 63, ty = threadIdx.x >> 6;
  const float* s = src + (size_t)h * D * DK;
#pragma unroll
  for (int i = 0; i < 16; ++i) {
    int row = i * 4 + ty;
    tile[row][tx] = s[(size_t)(d0 + row) * DK + k0 + tx];
  }
  __syncthreads();
  unsigned short* dd = dst + (size_t)h * DK * D;
#pragma unroll
  for (int i = 0; i < 16; ++i) {
    int kk = i * 4 + ty;
    dd[(size_t)(k0 + kk) * D + d0 + tx] = f2bf(tile[tx][kk]);
  }
}

// ---------------------------------------------------------------------------
// GEMM: C[m][n] = sum_k A[m][k] * Bt[n][k],  K = 1024, bf16 in, tile 128x128
// mode 0: C f32 [M][1024]
// mode 1: C bf16 per-head [B,H,T,64]   (row = b*T+t, col = h*64+k)
// mode 2: C bf16 VhT [B,H,64,T]        (row = h*64+v, col = b*T+t)
// ---------------------------------------------------------------------------
__global__ __launch_bounds__(256) void gemm_bt(
    const unsigned short* __restrict__ A, const unsigned short* __restrict__ Bt,
    void* __restrict__ C, int nTilesN, int mode, float scale) {
  __shared__ unsigned short As[128 * 64];
  __shared__ unsigned short Bs[128 * 64];
  const int bid = blockIdx.x;
  const int bm = bid / nTilesN, bn = bid % nTilesN;
  const int m0 = bm * 128, n0 = bn * 128;
  const int tid = threadIdx.x;
  const int wave = tid >> 6, lane = tid & 63;
  const int wr = wave >> 1, wc = wave & 1;

  f32x4 acc[4][4];
#pragma unroll
  for (int m = 0; m < 4; ++m)
#pragma unroll
    for (int n = 0; n < 4; ++n) acc[m][n] = 0.f;

  const int soff = wave * 1024 + lane * 16;
  const char* Afr = (const char*)As + (wr * 64 + (lane & 15)) * 128 + (lane >> 4) * 16;
  const char* Bfr = (const char*)Bs + (wc * 64 + (lane & 15)) * 128 + (lane >> 4) * 16;

  for (int kt = 0; kt < 16; ++kt) {
    __syncthreads();
#pragma unroll
    for (int i = 0; i < 4; ++i) {
      int o2 = i * 4096 + soff;
      int row = o2 >> 7, colb = o2 & 127;
      gload_lds16((const char*)(A + (size_t)(m0 + row) * 1024 + kt * 64) + colb,
                  (char*)As + i * 4096 + wave * 1024);
      gload_lds16((const char*)(Bt + (size_t)(n0 + row) * 1024 + kt * 64) + colb,
                  (char*)Bs + i * 4096 + wave * 1024);
    }
    __syncthreads();
#pragma unroll
    for (int kk = 0; kk < 2; ++kk) {
      bf16x8 af[4], bf[4];
#pragma unroll
      for (int m = 0; m < 4; ++m) af[m] = *(const bf16x8*)(Afr + m * 2048 + kk * 64);
#pragma unroll
      for (int n = 0; n < 4; ++n) bf[n] = *(const bf16x8*)(Bfr + n * 2048 + kk * 64);
#pragma unroll
      for (int m = 0; m < 4; ++m)
#pragma unroll
        for (int n = 0; n < 4; ++n) acc[m][n] = MFMA16(af[m], bf[n], acc[m][n]);
    }
  }

  const int rbase = m0 + wr * 64 + ((lane >> 4) << 2);
  const int cbase = n0 + wc * 64 + (lane & 15);
#pragma unroll
  for (int m = 0; m < 4; ++m)
#pragma unroll
    for (int n = 0; n < 4; ++n)
#pragma unroll
      for (int r = 0; r < 4; ++r) {
        int row = rbase + m * 16 + r;
        int col = cbase + n * 16;
        float v = acc[m][n][r] * scale;
        if (mode == 0) {
          ((float*)C)[(size_t)row * 1024 + col] = v;
        } else if (mode == 1) {
          int b = row >> 11, t = row & 2047, h = col >> 6, k = col & 63;
          ((unsigned short*)C)[(((size_t)(b * H_ + h) * T_) + t) * 64 + k] = f2bf(v);
        } else {
          int h = row >> 6, vv = row & 63, b = col >> 11, t = col & 2047;
          ((unsigned short*)C)[(((size_t)(b * H_ + h) * 64) + vv) * T_ + t] = f2bf(v);
        }
      }
}

// ---------------------------------------------------------------------------
// Flash attention (causal). One block = (b, h, 64 q-rows). 4 waves x 16 q-rows.
// Swapped QK^T: S^T = mfma(K, Q) so softmax state is lane-local (q = lane&15).
// Qh pre-scaled by log2(e)/8 -> pure exp2 softmax.
// ---------------------------------------------------------------------------
__global__ __launch_bounds__(256) void attn_fwd(
    const unsigned short* __restrict__ Qh, const unsigned short* __restrict__ Kh,
    const unsigned short* __restrict__ VhT, unsigned short* __restrict__ Abuf) {
  __shared__ unsigned short Ks[64 * 64];    // [s][k]
  __shared__ unsigned short Vs[64 * 64];    // [v][s]
  __shared__ unsigned short Ps[4][16 * 64]; // per-wave P [q][s]

  const int bid = blockIdx.x;
  const int qt = bid & 31;       // T/64
  const int bh = bid >> 5;       // b*H + h
  const int b = bh >> 4, h = bh & 15;
  const int tid = threadIdx.x;
  const int wave = tid >> 6, lane = tid & 63;
  const int lq = lane & 15;
  const int lk8 = (lane >> 4) * 8;
  const int q0 = qt * 64 + wave * 16;

  // Q fragment (B-operand of swapped QK^T): lane holds Q[q0+lq][k]
  bf16x8 qf0, qf1;
  {
    const unsigned short* qp = Qh + ((size_t)bh * T_ + q0 + lq) * 64 + lk8;
    qf0 = *(const bf16x8*)qp;
    qf1 = *(const bf16x8*)(qp + 32);
  }

  f32x4 o[4];
#pragma unroll
  for (int n = 0; n < 4; ++n) o[n] = 0.f;
  float m_run = -1e30f, l_run = 0.f;

  const int soff = wave * 1024 + lane * 16;

  for (int kt = 0; kt <= qt; ++kt) {
    const int s0 = kt * 64;
    __syncthreads();
#pragma unroll
    for (int i = 0; i < 2; ++i) {
      int o2 = i * 4096 + soff;
      int row = o2 >> 7, colb = o2 & 127;
      gload_lds16((const char*)(Kh + ((size_t)bh * T_ + s0 + row) * 64) + colb,
                  (char*)Ks + i * 4096 + wave * 1024);
      gload_lds16((const char*)(VhT + ((size_t)bh * 64 + row) * T_ + s0) + colb,
                  (char*)Vs + i * 4096 + wave * 1024);
    }
    __syncthreads();

    // S^T = mfma(K, Q): sacc[c] holds s rows c*16..+15, q cols = lane&15
    f32x4 sacc[4];
#pragma unroll
    for (int c = 0; c < 4; ++c) {
      sacc[c] = 0.f;
      const char* kb = (const char*)Ks + (c * 16 + lq) * 128 + lk8 * 2;
      bf16x8 ka0 = *(const bf16x8*)kb;
      bf16x8 ka1 = *(const bf16x8*)(kb + 64);
      sacc[c] = MFMA16(ka0, qf0, sacc[c]);
      sacc[c] = MFMA16(ka1, qf1, sacc[c]);
    }

    if (kt == qt) {
      int qg = q0 + lq;
#pragma unroll
      for (int c = 0; c < 4; ++c)
#pragma unroll
        for (int r = 0; r < 4; ++r) {
          int sg = s0 + c * 16 + ((lane >> 4) << 2) + r;
          if (sg > qg) sacc[c][r] = -1e30f;
        }
    }

    // online softmax (log2 domain), lane-local row q = lane&15
    float pmax = sacc[0][0];
#pragma unroll
    for (int c = 0; c < 4; ++c)
#pragma unroll
      for (int r = 0; r < 4; ++r) pmax = fmaxf(pmax, sacc[c][r]);
    pmax = fmaxf(pmax, __shfl_xor(pmax, 16));
    pmax = fmaxf(pmax, __shfl_xor(pmax, 32));
    float mnew = fmaxf(m_run, pmax);
    float corr = exp2f(m_run - mnew);
    float psum = 0.f;
#pragma unroll
    for (int c = 0; c < 4; ++c)
#pragma unroll
      for (int r = 0; r < 4; ++r) {
        float p = exp2f(sacc[c][r] - mnew);
        sacc[c][r] = p;
        psum += p;
      }
    psum += __shfl_xor(psum, 16);
    psum += __shfl_xor(psum, 32);
    l_run = l_run * corr + psum;
    m_run = mnew;

    // P -> LDS [q][s], 4 consecutive s per ds_write_b64
    unsigned short* pw = &Ps[wave][lq * 64 + ((lane >> 4) << 2)];
#pragma unroll
    for (int c = 0; c < 4; ++c) {
      u16x4 pk;
      pk[0] = f2bf(sacc[c][0]); pk[1] = f2bf(sacc[c][1]);
      pk[2] = f2bf(sacc[c][2]); pk[3] = f2bf(sacc[c][3]);
      *(u16x4*)(pw + c * 16) = pk;
    }

    // rescale O (rows q = 4*(lane>>4)+r; state lives at lane == that q)
    float cr[4];
#pragma unroll
    for (int r = 0; r < 4; ++r) cr[r] = __shfl(corr, ((lane >> 4) << 2) + r);
#pragma unroll
    for (int n = 0; n < 4; ++n)
#pragma unroll
      for (int r = 0; r < 4; ++r) o[n][r] *= cr[r];

    // O += P @ V
#pragma unroll
    for (int ks = 0; ks < 2; ++ks) {
      bf16x8 pa = *(const bf16x8*)(&Ps[wave][lq * 64 + ks * 32 + lk8]);
      const char* vbase = (const char*)Vs + lq * 128 + ks * 64 + lk8 * 2;
#pragma unroll
      for (int n = 0; n < 4; ++n)
        o[n] = MFMA16(pa, *(const bf16x8*)(vbase + n * 2048), o[n]);
    }
  }

  // finalize: divide by l, write A [b*T+t][h*64+v] bf16
  float inv[4];
#pragma unroll
  for (int r = 0; r < 4; ++r)
    inv[r] = 1.0f / __shfl(l_run, ((lane >> 4) << 2) + r);
#pragma unroll
  for (int r = 0; r < 4; ++r) {
    int t = qt * 64 + wave * 16 + ((lane >> 4) << 2) + r;
    size_t base = ((size_t)b * T_ + t) * 1024 + h * 64 + lq;
#pragma unroll
    for (int n = 0; n < 4; ++n)
      Abuf[base + n * 16] = f2bf(o[n][r] * inv[r]);
  }
}

// ---------------------------------------------------------------------------
extern "C" void kernel_launch(void* const* d_in, const int* in_sizes, int n_in,
                              void* d_out, int out_size, void* d_ws, size_t ws_size,
                              hipStream_t stream) {
  (void)in_sizes; (void)n_in; (void)out_size; (void)ws_size;
  const float* Q  = (const float*)d_in[0];
  const float* K  = (const float*)d_in[1];
  const float* V  = (const float*)d_in[2];
  const float* WQ = (const float*)d_in[3];
  const float* WK = (const float*)d_in[4];
  const float* WV = (const float*)d_in[5];
  const float* WO = (const float*)d_in[6];
  float* out = (float*)d_out;
  char* ws = (char*)d_ws;

  const size_t SZ_ACT = (size_t)8192 * 1024 * 2;  // 16.78 MB
  const size_t SZ_W   = (size_t)1024 * 1024 * 2;  //  2.10 MB
  unsigned short* Qbf = (unsigned short*)(ws);
  unsigned short* Kbf = (unsigned short*)(ws + SZ_ACT);
  unsigned short* Vbf = (unsigned short*)(ws + 2 * SZ_ACT);
  unsigned short* WqT = (unsigned short*)(ws + 3 * SZ_ACT);
  unsigned short* WkT = (unsigned short*)(ws + 3 * SZ_ACT + SZ_W);
  unsigned short* WvT = (unsigned short*)(ws + 3 * SZ_ACT + 2 * SZ_W);
  unsigned short* WOt = (unsigned short*)(ws + 3 * SZ_ACT + 3 * SZ_W);
  unsigned short* Qh  = (unsigned short*)(ws + 3 * SZ_ACT + 4 * SZ_W);
  unsigned short* Kh  = (unsigned short*)(ws + 4 * SZ_ACT + 4 * SZ_W);
  unsigned short* VhT = (unsigned short*)(ws + 5 * SZ_ACT + 4 * SZ_W);
  unsigned short* Abuf = Qbf;  // Qbf dead after Q projection

  // 1) convert activations to bf16
  conv_f32_bf16<<<2048, 256, 0, stream>>>((const float4*)Q, (u16x4*)Qbf, 2097152);
  conv_f32_bf16<<<2048, 256, 0, stream>>>((const float4*)K, (u16x4*)Kbf, 2097152);
  conv_f32_bf16<<<2048, 256, 0, stream>>>((const float4*)V, (u16x4*)Vbf, 2097152);

  // 2) transpose weights to B^T bf16
  transpose_w<<<256, 256, 0, stream>>>(WQ, WqT, 1024, 64, 16, 1);
  transpose_w<<<256, 256, 0, stream>>>(WK, WkT, 1024, 64, 16, 1);
  transpose_w<<<256, 256, 0, stream>>>(WV, WvT, 1024, 64, 16, 1);
  transpose_w<<<256, 256, 0, stream>>>(WO, WOt, 1024, 1024, 16, 16);

  // 3) projections (Q scaled by log2(e)/sqrt(dk))
  const float qscale = 1.4426950408889634f / 8.0f;
  gemm_bt<<<512, 256, 0, stream>>>(Qbf, WqT, Qh, 8, 1, qscale);   // M=8192,N=1024
  gemm_bt<<<512, 256, 0, stream>>>(Kbf, WkT, Kh, 8, 1, 1.0f);
  gemm_bt<<<512, 256, 0, stream>>>(WvT, Vbf, VhT, 64, 2, 1.0f);   // M=1024,N=8192 -> VhT

  // 4) causal flash attention
  attn_fwd<<<2048, 256, 0, stream>>>(Qh, Kh, VhT, Abuf);

  // 5) output projection -> f32
  gemm_bt<<<512, 256, 0, stream>>>(Abuf, WOt, out, 8, 0, 1.0f);
}